// Round 12
// baseline (147.651 us; speedup 1.0000x reference)
//
#include <hip/hip_runtime.h>

#define N_NODES 50000
#define N_EDGES 600000
#define DIM 128
#define NF4N (N_NODES * DIM / 4)              // 1,600,000
#define WTN (256 * 128)                       // 32,768
#define LINK_BLOCKS ((N_EDGES + 255) / 256)   // 2344
#define GEMM_TILES ((N_NODES + 63) / 64)      // 782

typedef __attribute__((ext_vector_type(8))) short short8;
typedef __attribute__((ext_vector_type(4))) float f32x4;

__device__ __forceinline__ unsigned bf16rne(float f) {
  unsigned x = __float_as_uint(f);
  x += 0x7fffu + ((x >> 16) & 1u);
  return x >> 16;
}

__device__ __forceinline__ uint2 pack4(float4 v) {
  uint2 o;
  o.x = bf16rne(v.x) | (bf16rne(v.y) << 16);
  o.y = bf16rne(v.z) | (bf16rne(v.w) << 16);
  return o;
}

// ---------------------------------------------------------------------------
// K1: head = -1; Wt bf16 remap; nf -> bf16.
// Wt[j][k] (j<128: W[j][k], the agg-half coefs; j>=128: W[j-128][128+k],
// the self-half coefs) -> 256 rows x 128 k, 256B rows = MFMA B operand.
// ---------------------------------------------------------------------------
__global__ __launch_bounds__(256) void k_init(
    const float4* __restrict__ nf4, uint2* __restrict__ nf16d,
    const float* __restrict__ Wf, unsigned short* __restrict__ wt,
    int* __restrict__ head) {
  int i = blockIdx.x * 256 + threadIdx.x;
  if (i < N_NODES) head[i] = -1;
  if (i < WTN) {
    int j = i >> 7, k = i & 127;
    float v = (j < 128) ? Wf[j * 256 + k] : Wf[(j - 128) * 256 + 128 + k];
    wt[i] = (unsigned short)bf16rne(v);
  }
  if (i < NF4N) nf16d[i] = pack4(nf4[i]);
}

// ---------------------------------------------------------------------------
// K2: heterogeneous. Blocks [0, LINK_BLOCKS): build per-dst linked list
// (next[e] = atomicExch(&head[dst[e]], e) — one atomic + coalesced store).
// Blocks [LINK_BLOCKS, +GEMM_TILES): MFMA tile of Y = nf16 @ Wt^T (K=128):
// 64 nodes x 256 j; wave wv -> j in [wv*64, +64); j<128 -> Y1 bf16,
// j>=128 -> Y2 = . + bias, bf16. Independent of the link phase.
// ---------------------------------------------------------------------------
__global__ __launch_bounds__(256) void k_link_gemm(
    const int* __restrict__ dst, int* __restrict__ head, int* __restrict__ next,
    const char* __restrict__ nf16, const char* __restrict__ wt,
    const float* __restrict__ bias,
    unsigned short* __restrict__ y1, unsigned short* __restrict__ y2) {
  if (blockIdx.x < LINK_BLOCKS) {
    int e = blockIdx.x * 256 + threadIdx.x;
    if (e < N_EDGES) next[e] = atomicExch(&head[dst[e]], e);
    return;
  }
  const int tile = blockIdx.x - LINK_BLOCKS;
  const int node0 = tile * 64;
  const int tid = threadIdx.x;
  const int lane = tid & 63;
  const int wv = tid >> 6;
  const int l16 = lane & 15, lg = lane >> 4;

  f32x4 acc[4][4] = {};
#pragma unroll
  for (int ks = 0; ks < 4; ++ks) {           // K = 128 = 4 x 32
    short8 a[4], bb[4];
#pragma unroll
    for (int m = 0; m < 4; ++m) {
      int node = node0 + m * 16 + l16;
      if (node > N_NODES - 1) node = N_NODES - 1;   // tail: masked at store
      a[m] = *reinterpret_cast<const short8*>(nf16 + (size_t)node * 256 + ks * 64 + lg * 16);
    }
#pragma unroll
    for (int n = 0; n < 4; ++n) {
      int j = wv * 64 + n * 16 + l16;
      bb[n] = *reinterpret_cast<const short8*>(wt + (size_t)j * 256 + ks * 64 + lg * 16);
    }
#pragma unroll
    for (int m = 0; m < 4; ++m)
#pragma unroll
      for (int n = 0; n < 4; ++n)
        acc[m][n] = __builtin_amdgcn_mfma_f32_16x16x32_bf16(a[m], bb[n], acc[m][n], 0, 0, 0);
  }

  // C frag: col = l16 (j), row = lg*4 + jj (node)
#pragma unroll
  for (int m = 0; m < 4; ++m) {
    int row_base = node0 + m * 16 + lg * 4;
#pragma unroll
    for (int n = 0; n < 4; ++n) {
      int j = wv * 64 + n * 16 + l16;
      float badd = (j >= 128) ? bias[j - 128] : 0.0f;
#pragma unroll
      for (int jj = 0; jj < 4; ++jj) {
        int node = row_base + jj;
        if (node < N_NODES) {
          unsigned h = bf16rne(acc[m][n][jj] + badd);
          if (j < 128) y1[(size_t)node * 128 + j] = (unsigned short)h;
          else         y2[(size_t)node * 128 + (j - 128)] = (unsigned short)h;
        }
      }
    }
  }
}

// ---------------------------------------------------------------------------
// K3: gather-final. Each wave walks TWO nodes' linked lists (2 independent
// dependent-load chains in flight); 64 lanes each hold 2 columns (4B of the
// 256B Y1 row). out[n] = (1/max(cnt,1)) * sum_e w_e * Y1[src_e] + Y2[n].
// Wave-uniform control flow (e0/e1 uniform); next[] chain is L2-hot 4B.
// ---------------------------------------------------------------------------
__global__ __launch_bounds__(256) void k_gather(
    const int* __restrict__ head, const int* __restrict__ next,
    const int* __restrict__ src, const float* __restrict__ ew,
    const unsigned* __restrict__ y1u, const unsigned* __restrict__ y2u,
    float2* __restrict__ out2) {
  int wid = blockIdx.x * 4 + (threadIdx.x >> 6);   // 25000 waves
  int lane = threadIdx.x & 63;
  int n0 = wid * 2, n1 = wid * 2 + 1;              // 50000 = 6250*4*2 exact
  int e0 = head[n0], e1 = head[n1];
  float a00 = 0.f, a01 = 0.f, a10 = 0.f, a11 = 0.f;
  int c0 = 0, c1 = 0;
  while (e0 >= 0 || e1 >= 0) {
    if (e0 >= 0) {
      int s = src[e0];
      float w = ew[e0];
      int en = next[e0];
      unsigned u = y1u[(size_t)s * 64 + lane];
      a00 += __uint_as_float(u << 16) * w;
      a01 += __uint_as_float(u & 0xffff0000u) * w;
      ++c0;
      e0 = en;
    }
    if (e1 >= 0) {
      int s = src[e1];
      float w = ew[e1];
      int en = next[e1];
      unsigned u = y1u[(size_t)s * 64 + lane];
      a10 += __uint_as_float(u << 16) * w;
      a11 += __uint_as_float(u & 0xffff0000u) * w;
      ++c1;
      e1 = en;
    }
  }
  {
    float inv = 1.0f / (float)max(c0, 1);
    unsigned uy = y2u[(size_t)n0 * 64 + lane];
    out2[(size_t)n0 * 64 + lane] =
        make_float2(a00 * inv + __uint_as_float(uy << 16),
                    a01 * inv + __uint_as_float(uy & 0xffff0000u));
  }
  {
    float inv = 1.0f / (float)max(c1, 1);
    unsigned uy = y2u[(size_t)n1 * 64 + lane];
    out2[(size_t)n1 * 64 + lane] =
        make_float2(a10 * inv + __uint_as_float(uy << 16),
                    a11 * inv + __uint_as_float(uy & 0xffff0000u));
  }
}

extern "C" void kernel_launch(void* const* d_in, const int* in_sizes, int n_in,
                              void* d_out, int out_size, void* d_ws, size_t ws_size,
                              hipStream_t stream) {
  const float* nf  = (const float*)d_in[0];  // [N, 128]
  const float* ew  = (const float*)d_in[1];  // [E, 1]
  const float* W   = (const float*)d_in[2];  // [128, 256]
  const float* b   = (const float*)d_in[3];  // [128]
  const int*   src = (const int*)d_in[4];    // [E]
  const int*   dst = (const int*)d_in[5];    // [E]
  float* out = (float*)d_out;                // [N, 128] f32

  // workspace layout (~41 MB of ~256 MiB ws), all 16B-aligned offsets
  char* ws = (char*)d_ws;
  char* nf16 = ws;                                    // 12,800,000
  char* wt   = nf16 + (size_t)N_NODES * DIM * 2;      // 65,536
  char* y1   = wt + (size_t)WTN * 2;                  // 12,800,000
  char* y2   = y1 + (size_t)N_NODES * DIM * 2;        // 12,800,000
  int*  head = (int*)(y2 + (size_t)N_NODES * DIM * 2);// 200,000
  int*  next = head + N_NODES;                        // 2,400,000

  k_init<<<NF4N / 256, 256, 0, stream>>>(
      (const float4*)nf, (uint2*)nf16, W, (unsigned short*)wt, head);
  k_link_gemm<<<LINK_BLOCKS + GEMM_TILES, 256, 0, stream>>>(
      dst, head, next, nf16, wt, b,
      (unsigned short*)y1, (unsigned short*)y2);
  k_gather<<<N_NODES / 8, 256, 0, stream>>>(
      head, next, src, ew, (const unsigned*)y1, (const unsigned*)y2,
      (float2*)out);
}

// Round 13
// 119.331 us; speedup vs baseline: 1.2373x; 1.2373x over previous
//
#include <hip/hip_runtime.h>

#define N_NODES 50000
#define N_EDGES 600000
#define DIM 128
#define NF4N (N_NODES * DIM / 4)              // 1,600,000
#define WTN (256 * 128)                       // 32,768
#define HIST_BLOCKS ((N_EDGES + 255) / 256)   // 2344
#define GEMM_TILES ((N_NODES + 63) / 64)      // 782
#define SCAN_BLOCKS ((N_NODES + 255) / 256)   // 196

typedef __attribute__((ext_vector_type(8))) short short8;
typedef __attribute__((ext_vector_type(4))) float f32x4;

__device__ __forceinline__ unsigned bf16rne(float f) {
  unsigned x = __float_as_uint(f);
  x += 0x7fffu + ((x >> 16) & 1u);
  return x >> 16;
}

__device__ __forceinline__ uint2 pack4(float4 v) {
  uint2 o;
  o.x = bf16rne(v.x) | (bf16rne(v.y) << 16);
  o.y = bf16rne(v.z) | (bf16rne(v.w) << 16);
  return o;
}

__device__ __forceinline__ void fma8(float* a, uint4 v, float w) {
  a[0] += __uint_as_float(v.x << 16) * w;
  a[1] += __uint_as_float(v.x & 0xffff0000u) * w;
  a[2] += __uint_as_float(v.y << 16) * w;
  a[3] += __uint_as_float(v.y & 0xffff0000u) * w;
  a[4] += __uint_as_float(v.z << 16) * w;
  a[5] += __uint_as_float(v.z & 0xffff0000u) * w;
  a[6] += __uint_as_float(v.w << 16) * w;
  a[7] += __uint_as_float(v.w & 0xffff0000u) * w;
}

// ---------------------------------------------------------------------------
// K1: deg = 0, gtotal = 0, W -> Wt bf16 remap, nf -> bf16.
// Wt[j][k]: j<128 -> W[j][k] (agg-half); j>=128 -> W[j-128][128+k] (self-half)
// ---------------------------------------------------------------------------
__global__ __launch_bounds__(256) void k_init(
    const float4* __restrict__ nf4, uint2* __restrict__ nf16d,
    const float* __restrict__ Wf, unsigned short* __restrict__ wt,
    int* __restrict__ deg, int* __restrict__ gtotal) {
  int i = blockIdx.x * 256 + threadIdx.x;
  if (i == 0) *gtotal = 0;
  if (i < N_NODES) deg[i] = 0;
  if (i < WTN) {
    int j = i >> 7, k = i & 127;
    float v = (j < 128) ? Wf[j * 256 + k] : Wf[(j - 128) * 256 + 128 + k];
    wt[i] = (unsigned short)bf16rne(v);
  }
  if (i < NF4N) nf16d[i] = pack4(nf4[i]);
}

// ---------------------------------------------------------------------------
// K2: heterogeneous. Blocks [0, HIST_BLOCKS): rank[e] = deg[dst[e]]++
// (atomic return -> coalesced store). Blocks [HIST_BLOCKS, +GEMM_TILES):
// MFMA tile of Y = nf16 @ Wt^T (K=128): 64 nodes x 256 j; wave wv -> j in
// [wv*64,+64); j<128 -> Y1 bf16, j>=128 -> Y2 = .+bias bf16. Independent.
// ---------------------------------------------------------------------------
__global__ __launch_bounds__(256) void k_hist_gemm(
    const int* __restrict__ dst, int* __restrict__ deg, int* __restrict__ rank,
    const char* __restrict__ nf16, const char* __restrict__ wt,
    const float* __restrict__ bias,
    unsigned short* __restrict__ y1, unsigned short* __restrict__ y2) {
  if (blockIdx.x < HIST_BLOCKS) {
    int e = blockIdx.x * 256 + threadIdx.x;
    if (e < N_EDGES) rank[e] = atomicAdd(&deg[dst[e]], 1);
    return;
  }
  const int tile = blockIdx.x - HIST_BLOCKS;
  const int node0 = tile * 64;
  const int tid = threadIdx.x;
  const int lane = tid & 63;
  const int wv = tid >> 6;
  const int l16 = lane & 15, lg = lane >> 4;

  f32x4 acc[4][4] = {};
#pragma unroll
  for (int ks = 0; ks < 4; ++ks) {           // K = 128 = 4 x 32
    short8 a[4], bb[4];
#pragma unroll
    for (int m = 0; m < 4; ++m) {
      int node = node0 + m * 16 + l16;
      if (node > N_NODES - 1) node = N_NODES - 1;   // tail: masked at store
      a[m] = *reinterpret_cast<const short8*>(nf16 + (size_t)node * 256 + ks * 64 + lg * 16);
    }
#pragma unroll
    for (int n = 0; n < 4; ++n) {
      int j = wv * 64 + n * 16 + l16;
      bb[n] = *reinterpret_cast<const short8*>(wt + (size_t)j * 256 + ks * 64 + lg * 16);
    }
#pragma unroll
    for (int m = 0; m < 4; ++m)
#pragma unroll
      for (int n = 0; n < 4; ++n)
        acc[m][n] = __builtin_amdgcn_mfma_f32_16x16x32_bf16(a[m], bb[n], acc[m][n], 0, 0, 0);
  }

  // C frag: col = l16 (j), row = lg*4 + jj (node)
#pragma unroll
  for (int m = 0; m < 4; ++m) {
    int row_base = node0 + m * 16 + lg * 4;
#pragma unroll
    for (int n = 0; n < 4; ++n) {
      int j = wv * 64 + n * 16 + l16;
      float badd = (j >= 128) ? bias[j - 128] : 0.0f;
#pragma unroll
      for (int jj = 0; jj < 4; ++jj) {
        int node = row_base + jj;
        if (node < N_NODES) {
          unsigned h = bf16rne(acc[m][n][jj] + badd);
          if (j < 128) y1[(size_t)node * 128 + j] = (unsigned short)h;
          else         y2[(size_t)node * 128 + (j - 128)] = (unsigned short)h;
        }
      }
    }
  }
}

// ---------------------------------------------------------------------------
// K3: fused exclusive scan of deg -> cursor; block base via atomicAdd
// (arrival order fine — CSR buckets only need disjointness). Proven.
// ---------------------------------------------------------------------------
__global__ __launch_bounds__(256) void k_scan(
    const int* __restrict__ deg, int* __restrict__ cursor,
    int* __restrict__ gtotal) {
  __shared__ int s[256];
  __shared__ int base;
  int t = threadIdx.x;
  int i = blockIdx.x * 256 + t;
  int v = (i < N_NODES) ? deg[i] : 0;
  s[t] = v;
  __syncthreads();
#pragma unroll
  for (int d = 1; d < 256; d <<= 1) {
    int add = (t >= d) ? s[t - d] : 0;
    __syncthreads();
    s[t] += add;
    __syncthreads();
  }
  int incl = s[t];
  if (t == 255) base = atomicAdd(gtotal, incl);
  __syncthreads();
  if (i < N_NODES) cursor[i] = base + incl - v;
}

// ---------------------------------------------------------------------------
// K4: srcw[cursor[dst[e]] + rank[e]] = src | (u16(w*65535) << 16)  (no atomics)
// ---------------------------------------------------------------------------
__global__ __launch_bounds__(256) void k_scatter(
    const int* __restrict__ src, const int* __restrict__ dst,
    const float* __restrict__ ew, const int* __restrict__ cursor,
    const int* __restrict__ rank, unsigned* __restrict__ srcw) {
  int e = blockIdx.x * 256 + threadIdx.x;
  if (e >= N_EDGES) return;
  int pos = cursor[dst[e]] + rank[e];
  unsigned wq = (unsigned)rintf(ew[e] * 65535.0f);
  srcw[pos] = (unsigned)src[e] | (wq << 16);
}

// ---------------------------------------------------------------------------
// K5: gather-final (r6-proven 8x8 structure over sequential CSR bucket).
// out[n] = (sum_e w_e * Y1[src_e]) / max(deg,1) + Y2[n]   (f32 write)
// wave = 8 edge-groups x 8 lanes; lane c holds 32B chunk c of the 256B row.
// ---------------------------------------------------------------------------
__global__ __launch_bounds__(256) void k_gather(
    const uint4* __restrict__ y1q,   // [N][16] granules of 8 bf16
    const uint4* __restrict__ y2q,
    const int* __restrict__ cursor, const int* __restrict__ deg,
    const unsigned* __restrict__ srcw, float4* __restrict__ out4) {
  int node = blockIdx.x * 4 + (threadIdx.x >> 6);
  int lane = threadIdx.x & 63;
  int g = lane >> 3;          // edge group 0..7
  int c = lane & 7;           // 32B chunk 0..7
  int dg = deg[node];
  int off = cursor[node];

  float a[16];
#pragma unroll
  for (int k = 0; k < 16; ++k) a[k] = 0.f;

  for (int j = g; j < dg; j += 8) {
    unsigned q = srcw[off + j];
    float w = (float)(q >> 16) * (1.0f / 65535.0f);
    const uint4* rp = y1q + (size_t)(q & 0xffffu) * 16 + c * 2;
    uint4 v0 = rp[0];
    uint4 v1 = rp[1];
    fma8(a, v0, w);
    fma8(a + 8, v1, w);
  }
#pragma unroll
  for (int k = 0; k < 16; ++k) {
    a[k] += __shfl_xor(a[k], 8);
    a[k] += __shfl_xor(a[k], 16);
    a[k] += __shfl_xor(a[k], 32);
  }
  if (g == 0) {
    float inv = 1.0f / (float)max(dg, 1);
    uint4 u0 = y2q[(size_t)node * 16 + c * 2];
    uint4 u1 = y2q[(size_t)node * 16 + c * 2 + 1];
    float4 o0, o1, o2, o3;
    o0.x = a[0] * inv + __uint_as_float(u0.x << 16);
    o0.y = a[1] * inv + __uint_as_float(u0.x & 0xffff0000u);
    o0.z = a[2] * inv + __uint_as_float(u0.y << 16);
    o0.w = a[3] * inv + __uint_as_float(u0.y & 0xffff0000u);
    o1.x = a[4] * inv + __uint_as_float(u0.z << 16);
    o1.y = a[5] * inv + __uint_as_float(u0.z & 0xffff0000u);
    o1.z = a[6] * inv + __uint_as_float(u0.w << 16);
    o1.w = a[7] * inv + __uint_as_float(u0.w & 0xffff0000u);
    o2.x = a[8] * inv + __uint_as_float(u1.x << 16);
    o2.y = a[9] * inv + __uint_as_float(u1.x & 0xffff0000u);
    o2.z = a[10] * inv + __uint_as_float(u1.y << 16);
    o2.w = a[11] * inv + __uint_as_float(u1.y & 0xffff0000u);
    o3.x = a[12] * inv + __uint_as_float(u1.z << 16);
    o3.y = a[13] * inv + __uint_as_float(u1.z & 0xffff0000u);
    o3.z = a[14] * inv + __uint_as_float(u1.w << 16);
    o3.w = a[15] * inv + __uint_as_float(u1.w & 0xffff0000u);
    float4* op = out4 + (size_t)node * 32 + c * 4;
    op[0] = o0; op[1] = o1; op[2] = o2; op[3] = o3;
  }
}

extern "C" void kernel_launch(void* const* d_in, const int* in_sizes, int n_in,
                              void* d_out, int out_size, void* d_ws, size_t ws_size,
                              hipStream_t stream) {
  const float* nf  = (const float*)d_in[0];  // [N, 128]
  const float* ew  = (const float*)d_in[1];  // [E, 1]
  const float* W   = (const float*)d_in[2];  // [128, 256]
  const float* b   = (const float*)d_in[3];  // [128]
  const int*   src = (const int*)d_in[4];    // [E]
  const int*   dst = (const int*)d_in[5];    // [E]
  float* out = (float*)d_out;                // [N, 128] f32

  // workspace layout (~43.7 MB of ~256 MiB ws), 16B-aligned offsets
  char* ws = (char*)d_ws;
  char* nf16 = ws;                                     // 12,800,000
  char* wt   = nf16 + (size_t)N_NODES * DIM * 2;       // 65,536
  char* y1   = wt + (size_t)WTN * 2;                   // 12,800,000
  char* y2   = y1 + (size_t)N_NODES * DIM * 2;         // 12,800,000
  int*  deg    = (int*)(y2 + (size_t)N_NODES * DIM * 2); // 200,000
  int*  cursor = deg + N_NODES;                        // 200,000
  int*  gtotal = cursor + N_NODES;                     // 4 (+pad to 1KB)
  int*  rank   = gtotal + 256;                         // 2,400,000
  unsigned* srcw = (unsigned*)(rank + N_EDGES);        // 2,400,000

  k_init<<<NF4N / 256, 256, 0, stream>>>(
      (const float4*)nf, (uint2*)nf16, W, (unsigned short*)wt, deg, gtotal);
  k_hist_gemm<<<HIST_BLOCKS + GEMM_TILES, 256, 0, stream>>>(
      dst, deg, rank, nf16, wt, b, (unsigned short*)y1, (unsigned short*)y2);
  k_scan<<<SCAN_BLOCKS, 256, 0, stream>>>(deg, cursor, gtotal);
  k_scatter<<<(N_EDGES + 255) / 256, 256, 0, stream>>>(
      src, dst, ew, cursor, rank, srcw);
  k_gather<<<N_NODES / 4, 256, 0, stream>>>(
      (const uint4*)y1, (const uint4*)y2, cursor, deg, srcw, (float4*)out);
}

// Round 14
// 105.723 us; speedup vs baseline: 1.3966x; 1.1287x over previous
//
#include <hip/hip_runtime.h>

#define N_NODES 50000
#define N_EDGES 600000
#define DIM 128
#define NF4N (N_NODES * DIM / 4)              // 1,600,000
#define WTN (256 * 128)                       // 32,768
#define HIST_BLOCKS ((N_EDGES + 255) / 256)   // 2344
#define GEMM_TILES ((N_NODES + 63) / 64)      // 782
#define SCAN_BLOCKS ((N_NODES + 255) / 256)   // 196

typedef __attribute__((ext_vector_type(8))) short short8;
typedef __attribute__((ext_vector_type(4))) float f32x4;

__device__ __forceinline__ unsigned bf16rne(float f) {
  unsigned x = __float_as_uint(f);
  x += 0x7fffu + ((x >> 16) & 1u);
  return x >> 16;
}

__device__ __forceinline__ uint2 pack4(float4 v) {
  uint2 o;
  o.x = bf16rne(v.x) | (bf16rne(v.y) << 16);
  o.y = bf16rne(v.z) | (bf16rne(v.w) << 16);
  return o;
}

__device__ __forceinline__ void fma8(float* a, uint4 v, float w) {
  a[0] += __uint_as_float(v.x << 16) * w;
  a[1] += __uint_as_float(v.x & 0xffff0000u) * w;
  a[2] += __uint_as_float(v.y << 16) * w;
  a[3] += __uint_as_float(v.y & 0xffff0000u) * w;
  a[4] += __uint_as_float(v.z << 16) * w;
  a[5] += __uint_as_float(v.z & 0xffff0000u) * w;
  a[6] += __uint_as_float(v.w << 16) * w;
  a[7] += __uint_as_float(v.w & 0xffff0000u) * w;
}

// ---------------------------------------------------------------------------
// K1: deg = 0, gtotal = 0, W -> Wt bf16 remap, nf -> bf16.
// Wt[j][k]: j<128 -> W[j][k] (agg-half); j>=128 -> W[j-128][128+k] (self-half)
// ---------------------------------------------------------------------------
__global__ __launch_bounds__(256) void k_init(
    const float4* __restrict__ nf4, uint2* __restrict__ nf16d,
    const float* __restrict__ Wf, unsigned short* __restrict__ wt,
    int* __restrict__ deg, int* __restrict__ gtotal) {
  int i = blockIdx.x * 256 + threadIdx.x;
  if (i == 0) *gtotal = 0;
  if (i < N_NODES) deg[i] = 0;
  if (i < WTN) {
    int j = i >> 7, k = i & 127;
    float v = (j < 128) ? Wf[j * 256 + k] : Wf[(j - 128) * 256 + 128 + k];
    wt[i] = (unsigned short)bf16rne(v);
  }
  if (i < NF4N) nf16d[i] = pack4(nf4[i]);
}

// ---------------------------------------------------------------------------
// K2: heterogeneous. Blocks [0, HIST_BLOCKS): rank[e] = deg[dst[e]]++.
// Blocks [HIST_BLOCKS, +GEMM_TILES): MFMA tile Y^T-style:
//   mfma(A=wt_frag, B=nf_frag) -> C[j][node]: col(lane&15)=node,
//   row(lg*4+jj)=j -> each lane holds 4 CONSECUTIVE j of one node's row
//   -> packed 8B dwordx2 stores (r13 post-mortem: 2B scalar stores were
//   the 64us bottleneck). Wave wv covers j in [wv*64,+64): wv<2 -> Y1,
//   wv>=2 -> Y2 (+bias, float4-loaded).
// ---------------------------------------------------------------------------
__global__ __launch_bounds__(256) void k_hist_gemm(
    const int* __restrict__ dst, int* __restrict__ deg, int* __restrict__ rank,
    const char* __restrict__ nf16, const char* __restrict__ wt,
    const float* __restrict__ bias,
    unsigned short* __restrict__ y1, unsigned short* __restrict__ y2) {
  if (blockIdx.x < HIST_BLOCKS) {
    int e = blockIdx.x * 256 + threadIdx.x;
    if (e < N_EDGES) rank[e] = atomicAdd(&deg[dst[e]], 1);
    return;
  }
  const int tile = blockIdx.x - HIST_BLOCKS;
  const int node0 = tile * 64;
  const int tid = threadIdx.x;
  const int lane = tid & 63;
  const int wv = tid >> 6;
  const int l16 = lane & 15, lg = lane >> 4;

  f32x4 acc[4][4] = {};   // [m: node frag][n: j frag]
#pragma unroll
  for (int ks = 0; ks < 4; ++ks) {           // K = 128 = 4 x 32
    short8 anf[4], awt[4];
#pragma unroll
    for (int m = 0; m < 4; ++m) {
      int node = node0 + m * 16 + l16;
      if (node > N_NODES - 1) node = N_NODES - 1;   // tail: masked at store
      anf[m] = *reinterpret_cast<const short8*>(nf16 + (size_t)node * 256 + ks * 64 + lg * 16);
    }
#pragma unroll
    for (int n = 0; n < 4; ++n) {
      int j = wv * 64 + n * 16 + l16;
      awt[n] = *reinterpret_cast<const short8*>(wt + (size_t)j * 256 + ks * 64 + lg * 16);
    }
#pragma unroll
    for (int m = 0; m < 4; ++m)
#pragma unroll
      for (int n = 0; n < 4; ++n)
        acc[m][n] = __builtin_amdgcn_mfma_f32_16x16x32_bf16(awt[n], anf[m], acc[m][n], 0, 0, 0);
  }

  // epilogue: per (m,n) one packed 8B store of 4 consecutive j
  const bool isY2 = (wv >= 2);
  unsigned short* yb = isY2 ? y2 : y1;
  const int jhalf = (wv & 1) * 64;
#pragma unroll
  for (int n = 0; n < 4; ++n) {
    int jb = jhalf + n * 16 + lg * 4;        // j offset within the 128-half
    float4 bv = make_float4(0.f, 0.f, 0.f, 0.f);
    if (isY2) bv = *reinterpret_cast<const float4*>(bias + jb);
#pragma unroll
    for (int m = 0; m < 4; ++m) {
      int node = node0 + m * 16 + l16;
      if (node >= N_NODES) continue;
      uint2 st;
      st.x = bf16rne(acc[m][n][0] + bv.x) | (bf16rne(acc[m][n][1] + bv.y) << 16);
      st.y = bf16rne(acc[m][n][2] + bv.z) | (bf16rne(acc[m][n][3] + bv.w) << 16);
      *reinterpret_cast<uint2*>(yb + (size_t)node * 128 + jb) = st;
    }
  }
}

// ---------------------------------------------------------------------------
// K3: fused exclusive scan of deg -> cursor; block base via atomicAdd
// (arrival order fine — CSR buckets only need disjointness). Proven.
// ---------------------------------------------------------------------------
__global__ __launch_bounds__(256) void k_scan(
    const int* __restrict__ deg, int* __restrict__ cursor,
    int* __restrict__ gtotal) {
  __shared__ int s[256];
  __shared__ int base;
  int t = threadIdx.x;
  int i = blockIdx.x * 256 + t;
  int v = (i < N_NODES) ? deg[i] : 0;
  s[t] = v;
  __syncthreads();
#pragma unroll
  for (int d = 1; d < 256; d <<= 1) {
    int add = (t >= d) ? s[t - d] : 0;
    __syncthreads();
    s[t] += add;
    __syncthreads();
  }
  int incl = s[t];
  if (t == 255) base = atomicAdd(gtotal, incl);
  __syncthreads();
  if (i < N_NODES) cursor[i] = base + incl - v;
}

// ---------------------------------------------------------------------------
// K4: srcw[cursor[dst[e]] + rank[e]] = src | (u16(w*65535) << 16)  (no atomics)
// ---------------------------------------------------------------------------
__global__ __launch_bounds__(256) void k_scatter(
    const int* __restrict__ src, const int* __restrict__ dst,
    const float* __restrict__ ew, const int* __restrict__ cursor,
    const int* __restrict__ rank, unsigned* __restrict__ srcw) {
  int e = blockIdx.x * 256 + threadIdx.x;
  if (e >= N_EDGES) return;
  int pos = cursor[dst[e]] + rank[e];
  unsigned wq = (unsigned)rintf(ew[e] * 65535.0f);
  srcw[pos] = (unsigned)src[e] | (wq << 16);
}

// ---------------------------------------------------------------------------
// K5: gather-final (r6-proven 8x8 structure over sequential CSR bucket).
// out[n] = (sum_e w_e * Y1[src_e]) / max(deg,1) + Y2[n]   (f32 write)
// ---------------------------------------------------------------------------
__global__ __launch_bounds__(256) void k_gather(
    const uint4* __restrict__ y1q,   // [N][16] granules of 8 bf16
    const uint4* __restrict__ y2q,
    const int* __restrict__ cursor, const int* __restrict__ deg,
    const unsigned* __restrict__ srcw, float4* __restrict__ out4) {
  int node = blockIdx.x * 4 + (threadIdx.x >> 6);
  int lane = threadIdx.x & 63;
  int g = lane >> 3;          // edge group 0..7
  int c = lane & 7;           // 32B chunk 0..7
  int dg = deg[node];
  int off = cursor[node];

  float a[16];
#pragma unroll
  for (int k = 0; k < 16; ++k) a[k] = 0.f;

  for (int j = g; j < dg; j += 8) {
    unsigned q = srcw[off + j];
    float w = (float)(q >> 16) * (1.0f / 65535.0f);
    const uint4* rp = y1q + (size_t)(q & 0xffffu) * 16 + c * 2;
    uint4 v0 = rp[0];
    uint4 v1 = rp[1];
    fma8(a, v0, w);
    fma8(a + 8, v1, w);
  }
#pragma unroll
  for (int k = 0; k < 16; ++k) {
    a[k] += __shfl_xor(a[k], 8);
    a[k] += __shfl_xor(a[k], 16);
    a[k] += __shfl_xor(a[k], 32);
  }
  if (g == 0) {
    float inv = 1.0f / (float)max(dg, 1);
    uint4 u0 = y2q[(size_t)node * 16 + c * 2];
    uint4 u1 = y2q[(size_t)node * 16 + c * 2 + 1];
    float4 o0, o1, o2, o3;
    o0.x = a[0] * inv + __uint_as_float(u0.x << 16);
    o0.y = a[1] * inv + __uint_as_float(u0.x & 0xffff0000u);
    o0.z = a[2] * inv + __uint_as_float(u0.y << 16);
    o0.w = a[3] * inv + __uint_as_float(u0.y & 0xffff0000u);
    o1.x = a[4] * inv + __uint_as_float(u0.z << 16);
    o1.y = a[5] * inv + __uint_as_float(u0.z & 0xffff0000u);
    o1.z = a[6] * inv + __uint_as_float(u0.w << 16);
    o1.w = a[7] * inv + __uint_as_float(u0.w & 0xffff0000u);
    o2.x = a[8] * inv + __uint_as_float(u1.x << 16);
    o2.y = a[9] * inv + __uint_as_float(u1.x & 0xffff0000u);
    o2.z = a[10] * inv + __uint_as_float(u1.y << 16);
    o2.w = a[11] * inv + __uint_as_float(u1.y & 0xffff0000u);
    o3.x = a[12] * inv + __uint_as_float(u1.z << 16);
    o3.y = a[13] * inv + __uint_as_float(u1.z & 0xffff0000u);
    o3.z = a[14] * inv + __uint_as_float(u1.w << 16);
    o3.w = a[15] * inv + __uint_as_float(u1.w & 0xffff0000u);
    float4* op = out4 + (size_t)node * 32 + c * 4;
    op[0] = o0; op[1] = o1; op[2] = o2; op[3] = o3;
  }
}

extern "C" void kernel_launch(void* const* d_in, const int* in_sizes, int n_in,
                              void* d_out, int out_size, void* d_ws, size_t ws_size,
                              hipStream_t stream) {
  const float* nf  = (const float*)d_in[0];  // [N, 128]
  const float* ew  = (const float*)d_in[1];  // [E, 1]
  const float* W   = (const float*)d_in[2];  // [128, 256]
  const float* b   = (const float*)d_in[3];  // [128]
  const int*   src = (const int*)d_in[4];    // [E]
  const int*   dst = (const int*)d_in[5];    // [E]
  float* out = (float*)d_out;                // [N, 128] f32

  // workspace layout (~43.7 MB of ~256 MiB ws), 16B-aligned offsets
  char* ws = (char*)d_ws;
  char* nf16 = ws;                                     // 12,800,000
  char* wt   = nf16 + (size_t)N_NODES * DIM * 2;       // 65,536
  char* y1   = wt + (size_t)WTN * 2;                   // 12,800,000
  char* y2   = y1 + (size_t)N_NODES * DIM * 2;         // 12,800,000
  int*  deg    = (int*)(y2 + (size_t)N_NODES * DIM * 2); // 200,000
  int*  cursor = deg + N_NODES;                        // 200,000
  int*  gtotal = cursor + N_NODES;                     // 4 (+pad to 1KB)
  int*  rank   = gtotal + 256;                         // 2,400,000
  unsigned* srcw = (unsigned*)(rank + N_EDGES);        // 2,400,000

  k_init<<<NF4N / 256, 256, 0, stream>>>(
      (const float4*)nf, (uint2*)nf16, W, (unsigned short*)wt, deg, gtotal);
  k_hist_gemm<<<HIST_BLOCKS + GEMM_TILES, 256, 0, stream>>>(
      dst, deg, rank, nf16, wt, b, (unsigned short*)y1, (unsigned short*)y2);
  k_scan<<<SCAN_BLOCKS, 256, 0, stream>>>(deg, cursor, gtotal);
  k_scatter<<<(N_EDGES + 255) / 256, 256, 0, stream>>>(
      src, dst, ew, cursor, rank, srcw);
  k_gather<<<N_NODES / 4, 256, 0, stream>>>(
      (const uint4*)y1, (const uint4*)y2, cursor, deg, srcw, (float4*)out);
}